// Round 11
// baseline (173.813 us; speedup 1.0000x reference)
//
#include <hip/hip_runtime.h>
#include <math.h>

// Problem constants
#define Bn 32
#define Sn 16384
#define Kn 64
#define Nn 128

#define NSB 32           // blocks per batch (both passes) -> 1024 blocks
#define SPB (Sn/NSB)     // 512 samples per block
#define NCH (SPB/32)     // 16 chunks of 32 samples

typedef __attribute__((ext_vector_type(8))) short bf16x8;   // MFMA frag
typedef __attribute__((ext_vector_type(4))) float f32x4;

// workspace layout in floats
#define WS_CSPART 0                          // Bn*2*NSB*64 = 131072
#define WS_GRAM   (Bn*2*NSB*64)              // + Bn*3*4096 (atomic-fallback only)
#define WS_LOSS   (WS_GRAM + Bn*3*4096)      // + Bn
#define WS_PART   (WS_LOSS + Bn)             // + Bn*NSB*3*4096
#define WS_PART_SZ ((size_t)Bn*NSB*3*4096)

__device__ __forceinline__ unsigned short f2bf(float f) {
    unsigned int u = __float_as_uint(f);
    u += 0x7FFFu + ((u >> 16) & 1u);
    return (unsigned short)(u >> 16);
}

// ---------------- Pass 1: colsum via MFMA (gram-shaped pipeline; frozen) ----------------
__global__ __launch_bounds__(256, 4) void k_colsum(const float* __restrict__ qi,
                                                   const float* __restrict__ qj,
                                                   float* __restrict__ ws) {
    const int b   = blockIdx.x / NSB;
    const int sb  = blockIdx.x % NSB;
    const int tid = threadIdx.x;
    const int w   = tid >> 6;
    const int l   = tid & 63;
    const int lc  = tid & 15;
    const int sp  = tid >> 4;        // sample-pair 0..15
    const int c0  = lc * 4;

    __shared__ unsigned short lp[2][2][64 * 40];   // [buf][view][col][40], 20.5 KB

    f32x4 cs[2][4];
    #pragma unroll
    for (int v = 0; v < 2; ++v)
        #pragma unroll
        for (int nt = 0; nt < 4; ++nt) cs[v][nt] = (f32x4){0.f, 0.f, 0.f, 0.f};

    const long bb  = (long)b * Sn * Kn;
    const long s0g = (long)sb * SPB;

    float4 pfa[2], pfb[2];
    auto issue = [&](int ct) {
        const long off = bb + (s0g + ct * 32 + 2 * sp) * (long)Kn + c0;
        pfa[0] = *(const float4*)(qi + off);
        pfb[0] = *(const float4*)(qi + off + Kn);
        pfa[1] = *(const float4*)(qj + off);
        pfb[1] = *(const float4*)(qj + off + Kn);
    };
    auto stage = [&](int buf) {
        #pragma unroll
        for (int v = 0; v < 2; ++v) {
            const float4 qa = pfa[v], qb = pfb[v];
            const float ta[4] = {qa.x * qa.x, qa.y * qa.y, qa.z * qa.z, qa.w * qa.w};
            const float tb[4] = {qb.x * qb.x, qb.y * qb.y, qb.z * qb.z, qb.w * qb.w};
            #pragma unroll
            for (int cc = 0; cc < 4; ++cc) {
                const unsigned int pk = (unsigned int)f2bf(ta[cc])
                                      | ((unsigned int)f2bf(tb[cc]) << 16);
                *(unsigned int*)&lp[buf][v][(c0 + cc) * 40 + 2 * sp] = pk;
            }
        }
    };

    bf16x8 ones;
    #pragma unroll
    for (int e = 0; e < 8; ++e) ones[e] = (short)0x3F80;   // bf16 1.0

    issue(0);
    stage(0);
    issue(1);
    __syncthreads();

    const int sgo = (l >> 4) * 8;
    #pragma unroll 1
    for (int ct = 0; ct < NCH; ++ct) {
        const int cur = ct & 1;
        #pragma unroll
        for (int nt = 0; nt < 4; ++nt) {
            const bf16x8 fi = *(const bf16x8*)&lp[cur][0][(nt * 16 + lc) * 40 + sgo];
            const bf16x8 fj = *(const bf16x8*)&lp[cur][1][(nt * 16 + lc) * 40 + sgo];
            cs[0][nt] = __builtin_amdgcn_mfma_f32_16x16x32_bf16(ones, fi, cs[0][nt], 0, 0, 0);
            cs[1][nt] = __builtin_amdgcn_mfma_f32_16x16x32_bf16(ones, fj, cs[1][nt], 0, 0, 0);
        }
        if (ct + 1 < NCH) {
            stage(cur ^ 1);
            if (ct + 2 < NCH) issue(ct + 2);
        }
        __syncthreads();
    }

    // D row 0 (reg 0, lanes 0..15) = colsum of this block's 512 samples
    if (w == 0 && l < 16) {
        #pragma unroll
        for (int v = 0; v < 2; ++v)
            #pragma unroll
            for (int nt = 0; nt < 4; ++nt)
                ws[WS_CSPART + ((b * 2 + v) * NSB + sb) * 64 + nt * 16 + l] = cs[v][nt][0];
    }
}

// ---------------- Pass 2: normalize -> bf16 -> MFMA Gram (pipelined; frozen) ----------------
template<int ATOMIC>
__global__ __launch_bounds__(256, 4) void k_gram(const float* __restrict__ qi,
                                                 const float* __restrict__ qj,
                                                 float* __restrict__ ws) {
    const int b   = blockIdx.x / NSB;
    const int sb  = blockIdx.x % NSB;
    const int tid = threadIdx.x;
    const int w   = tid >> 6;
    const int l   = tid & 63;
    const int lc  = tid & 15;
    const int sp  = tid >> 4;
    const int c0  = lc * 4;

    __shared__ unsigned short lp[2][2][64 * 40];
    __shared__ float csh[128];

    if (tid < 128) {
        const int view = tid >> 6, col = tid & 63;
        float s = 0.f;
        #pragma unroll 8
        for (int p = 0; p < NSB; ++p)
            s += ws[WS_CSPART + ((b * 2 + view) * NSB + p) * 64 + col];
        csh[view * 64 + col] = s;
    }
    __syncthreads();

    const float icI[4] = {1.f / csh[c0], 1.f / csh[c0 + 1],
                          1.f / csh[c0 + 2], 1.f / csh[c0 + 3]};
    const float icJ[4] = {1.f / csh[64 + c0], 1.f / csh[64 + c0 + 1],
                          1.f / csh[64 + c0 + 2], 1.f / csh[64 + c0 + 3]};

    f32x4 aII[4], aIJ[4], aJJ[4];
    #pragma unroll
    for (int t = 0; t < 4; ++t) {
        aII[t] = (f32x4){0.f, 0.f, 0.f, 0.f};
        aIJ[t] = (f32x4){0.f, 0.f, 0.f, 0.f};
        aJJ[t] = (f32x4){0.f, 0.f, 0.f, 0.f};
    }

    const long bb  = (long)b * Sn * Kn;
    const long s0g = (long)sb * SPB;

    float4 pfa[2], pfb[2];
    auto issue = [&](int ct) {
        const long off = bb + (s0g + ct * 32 + 2 * sp) * (long)Kn + c0;
        pfa[0] = *(const float4*)(qi + off);
        pfb[0] = *(const float4*)(qi + off + Kn);
        pfa[1] = *(const float4*)(qj + off);
        pfb[1] = *(const float4*)(qj + off + Kn);
    };
    auto stage = [&](int buf) {
        #pragma unroll
        for (int v = 0; v < 2; ++v) {
            const float* ic = v ? icJ : icI;
            const float4 qa = pfa[v], qb = pfb[v];
            float wa[4] = {qa.x * qa.x * ic[0], qa.y * qa.y * ic[1],
                           qa.z * qa.z * ic[2], qa.w * qa.w * ic[3]};
            float wb[4] = {qb.x * qb.x * ic[0], qb.y * qb.y * ic[1],
                           qb.z * qb.z * ic[2], qb.w * qb.w * ic[3]};
            float ra = wa[0] + wa[1] + wa[2] + wa[3];
            float rb = wb[0] + wb[1] + wb[2] + wb[3];
            #pragma unroll
            for (int d = 1; d < 16; d <<= 1) {
                ra += __shfl_xor(ra, d);
                rb += __shfl_xor(rb, d);
            }
            const float ia = 1.f / ra, ib = 1.f / rb;
            #pragma unroll
            for (int cc = 0; cc < 4; ++cc) {
                const unsigned int pk = (unsigned int)f2bf(wa[cc] * ia)
                                      | ((unsigned int)f2bf(wb[cc] * ib) << 16);
                *(unsigned int*)&lp[buf][v][(c0 + cc) * 40 + 2 * sp] = pk;
            }
        }
    };

    issue(0);
    stage(0);
    issue(1);
    __syncthreads();

    const int sgo = (l >> 4) * 8;
    #pragma unroll 1
    for (int ct = 0; ct < NCH; ++ct) {
        const int cur = ct & 1;
        const bf16x8 ai = *(const bf16x8*)&lp[cur][0][(w * 16 + lc) * 40 + sgo];
        const bf16x8 aj = *(const bf16x8*)&lp[cur][1][(w * 16 + lc) * 40 + sgo];
        #pragma unroll
        for (int nt = 0; nt < 4; ++nt) {
            const bf16x8 fi = *(const bf16x8*)&lp[cur][0][(nt * 16 + lc) * 40 + sgo];
            const bf16x8 fj = *(const bf16x8*)&lp[cur][1][(nt * 16 + lc) * 40 + sgo];
            aII[nt] = __builtin_amdgcn_mfma_f32_16x16x32_bf16(ai, fi, aII[nt], 0, 0, 0);
            aIJ[nt] = __builtin_amdgcn_mfma_f32_16x16x32_bf16(ai, fj, aIJ[nt], 0, 0, 0);
            aJJ[nt] = __builtin_amdgcn_mfma_f32_16x16x32_bf16(aj, fj, aJJ[nt], 0, 0, 0);
        }
        if (ct + 1 < NCH) {
            stage(cur ^ 1);
            if (ct + 2 < NCH) issue(ct + 2);
        }
        __syncthreads();
    }

    const int row0 = w * 16 + (l >> 4) * 4;
    if (ATOMIC) {
        float* __restrict__ dst = ws + WS_GRAM + (long)b * 3 * 4096;
        #pragma unroll
        for (int nt = 0; nt < 4; ++nt) {
            #pragma unroll
            for (int r = 0; r < 4; ++r) {
                const int e = (row0 + r) * 64 + nt * 16 + lc;
                atomicAdd(&dst[e],        aII[nt][r]);
                atomicAdd(&dst[4096 + e], aIJ[nt][r]);
                atomicAdd(&dst[8192 + e], aJJ[nt][r]);
            }
        }
    } else {
        float* __restrict__ dst = ws + WS_PART + (long)(b * NSB + sb) * 3 * 4096;
        #pragma unroll
        for (int nt = 0; nt < 4; ++nt) {
            #pragma unroll
            for (int r = 0; r < 4; ++r) {
                const int e = (row0 + r) * 64 + nt * 16 + lc;
                dst[e]        = aII[nt][r];
                dst[4096 + e] = aIJ[nt][r];
                dst[8192 + e] = aJJ[nt][r];
            }
        }
    }
}

// ---------------- Pass 3: fold partials + masked-LSE loss (one kernel) ----------------
__device__ __forceinline__ float sim_entry(const float* g, int r, int c) {
    // sim = [[Gii, Gij], [Gij^T, Gjj]]
    if (r < 64) return (c < 64) ? g[r * 64 + c] : g[4096 + r * 64 + (c - 64)];
    return (c < 64) ? g[4096 + c * 64 + (r - 64)] : g[8192 + (r - 64) * 64 + (c - 64)];
}

template<int FROM_PART>
__global__ __launch_bounds__(256) void k_loss(const float* __restrict__ temp,
                                              float* __restrict__ ws) {
    const int b   = blockIdx.x;
    const int tid = threadIdx.x;
    __shared__ float sim[3 * 4096];   // 48 KB
    __shared__ float red[128];

    if (FROM_PART) {
        // fold the NSB per-block partials: 12288 elems / 256 thr = 12 f32x4 each
        #pragma unroll 1
        for (int qd = 0; qd < 12; ++qd) {
            const int e = (qd * 256 + tid) * 4;
            f32x4 s = {0.f, 0.f, 0.f, 0.f};
            #pragma unroll 8
            for (int p = 0; p < NSB; ++p)
                s += *(const f32x4*)&ws[WS_PART + (long)(b * NSB + p) * 3 * 4096 + e];
            *(f32x4*)&sim[e] = s;
        }
    } else {
        for (int qd = 0; qd < 12; ++qd) {
            const int e = (qd * 256 + tid) * 4;
            *(f32x4*)&sim[e] = *(const f32x4*)&ws[WS_GRAM + (long)b * 3 * 4096 + e];
        }
    }
    __syncthreads();

    float val = 0.f;
    if (tid < 128) {
        const int r = tid;
        const float inv_t = 1.f / temp[0];
        const int p = r ^ 64;
        float m = -1e30f, pos = 0.f;
        for (int c = 0; c < Nn; ++c) {
            if (c == r) continue;
            const float v = sim_entry(sim, r, c) * inv_t;
            m = fmaxf(m, v);
            if (c == p) pos = v;
        }
        float sum = 0.f;
        for (int c = 0; c < Nn; ++c) {
            if (c == r) continue;
            sum += expf(sim_entry(sim, r, c) * inv_t - m);
        }
        val = m + logf(sum) - pos;
        red[r] = val;
    }
    __syncthreads();
    for (int st = 64; st > 0; st >>= 1) {
        if (tid < st) red[tid] += red[tid + st];
        __syncthreads();
    }
    if (tid == 0) ws[WS_LOSS + b] = red[0] / (float)Nn;
}

__global__ void k_final(float* __restrict__ ws, float* __restrict__ out) {
    const int t = threadIdx.x;            // 64 threads
    float v = (t < Bn) ? ws[WS_LOSS + t] : 0.f;
    #pragma unroll
    for (int d = 1; d < 32; d <<= 1) v += __shfl_xor(v, d);
    if (t == 0) out[0] = v / (float)Bn;
}

extern "C" void kernel_launch(void* const* d_in, const int* in_sizes, int n_in,
                              void* d_out, int out_size, void* d_ws, size_t ws_size,
                              hipStream_t stream) {
    const float* qi   = (const float*)d_in[0];
    const float* qj   = (const float*)d_in[1];
    const float* temp = (const float*)d_in[2];
    float* ws  = (float*)d_ws;
    float* out = (float*)d_out;

    const size_t need_f = (size_t)WS_PART + WS_PART_SZ;
    const bool partial = ws_size >= need_f * sizeof(float);

    k_colsum<<<Bn * NSB, 256, 0, stream>>>(qi, qj, ws);

    if (partial) {
        k_gram<0><<<Bn * NSB, 256, 0, stream>>>(qi, qj, ws);
        k_loss<1><<<Bn, 256, 0, stream>>>(temp, ws);
    } else {
        hipMemsetAsync(ws + WS_GRAM, 0, (size_t)Bn * 3 * 4096 * sizeof(float), stream);
        k_gram<1><<<Bn * NSB, 256, 0, stream>>>(qi, qj, ws);
        k_loss<0><<<Bn, 256, 0, stream>>>(temp, ws);
    }

    k_final<<<1, 64, 0, stream>>>(ws, out);
}